// Round 15
// baseline (116.518 us; speedup 1.0000x reference)
//
#include <hip/hip_runtime.h>
#include <hip/hip_bf16.h>

// MultiHeadAttention: x[2,2048,1024] fp32 -> QKV proj + RoPE + softmax attn + O proj
// R15: attn blocks shrunk to 2 waves (64 q/block, KVBLK=64, K[2]/V[3] = 40KB)
// -> 4 independent blocks/CU; barriers sync only 2 waves, cross-block
// co-scheduling hides each block's stalls. 32x32 MFMA, in-register P, ones-MFMA
// row-sum (R12-R14 machinery). GEMMs/prep unchanged (R10 2-D grids).

#define SEQ    2048
#define BATCH  2
#define NHEADS 16
#define HDIM   64
#define HID    1024
#define NTOK   (BATCH*SEQ)   // 4096

typedef __bf16 bf16x8 __attribute__((ext_vector_type(8)));
typedef float  f32x4  __attribute__((ext_vector_type(4)));
typedef float  f32x16 __attribute__((ext_vector_type(16)));
typedef unsigned short u16x8 __attribute__((ext_vector_type(8)));
typedef unsigned int   u32x4 __attribute__((ext_vector_type(4)));

__device__ __forceinline__ unsigned short bfc(float x) {
  return __builtin_bit_cast(unsigned short, (__bf16)x);   // native v_cvt (RNE)
}
__device__ __forceinline__ unsigned int pk(float lo, float hi) {
  return (unsigned int)bfc(lo) | ((unsigned int)bfc(hi) << 16);
}
// swap upper 32 lanes of a with lower 32 lanes of b (gfx950)
__device__ __forceinline__ void plswap(unsigned int& a, unsigned int& b) {
  asm volatile("v_permlane32_swap_b32 %0, %1" : "+v"(a), "+v"(b));
}
#define EXP2(x) __builtin_amdgcn_exp2f(x)
#define MFMA32(a, b, c) __builtin_amdgcn_mfma_f32_32x32x16_bf16(a, b, c, 0, 0, 0)

// async global->LDS, 16B per lane. dest = wave-uniform base (+ lane*16 by HW).
__device__ __forceinline__ void gload16(const void* gptr, void* ldsptr) {
  typedef __attribute__((address_space(3))) unsigned int as3_uint;
  typedef const __attribute__((address_space(1))) unsigned int as1_uint;
  __builtin_amdgcn_global_load_lds(
      (as1_uint*)(unsigned long long)gptr,
      (as3_uint*)(unsigned int)(unsigned long long)ldsptr,
      16, 0, 0);
}

__device__ __forceinline__ void cvt8(const float* __restrict__ s,
                                     unsigned short* __restrict__ d, int i) {
  float4 a = *reinterpret_cast<const float4*>(s + i);
  float4 b = *reinterpret_cast<const float4*>(s + i + 4);
  u16x8 o;
  o[0] = bfc(a.x); o[1] = bfc(a.y); o[2] = bfc(a.z); o[3] = bfc(a.w);
  o[4] = bfc(b.x); o[5] = bfc(b.y); o[6] = bfc(b.z); o[7] = bfc(b.w);
  *reinterpret_cast<u16x8*>(d + i) = o;
}

// ---------------- prep: all converts + rope tables in ONE launch ----------------
__global__ __launch_bounds__(256) void prep(
    const float* __restrict__ x,
    const float* __restrict__ qw, const float* __restrict__ kw,
    const float* __restrict__ vw, const float* __restrict__ ow,
    unsigned short* __restrict__ xb,
    unsigned short* __restrict__ wqb, unsigned short* __restrict__ wkb,
    unsigned short* __restrict__ wvb, unsigned short* __restrict__ wob,
    float* __restrict__ ct, float* __restrict__ st)
{
  const int XN = NTOK * HID / 8;   // 524288
  const int WN = HID * HID / 8;    // 131072 (pow2)
  int tid = blockIdx.x * 256 + threadIdx.x;
  if (tid < XN) {
    cvt8(x, xb, tid * 8);
  } else if (tid < XN + 4 * WN) {
    int r = tid - XN;
    int which = r >> 17;                 // / 131072
    int i = (r & (WN - 1)) * 8;
    const float* s = (which == 0) ? qw : (which == 1) ? kw : (which == 2) ? vw : ow;
    unsigned short* d = (which == 0) ? wqb : (which == 1) ? wkb : (which == 2) ? wvb : wob;
    cvt8(s, d, i);
  } else {
    int idx = tid - (XN + 4 * WN);
    if (idx < SEQ * 32) {
      int p = idx >> 5, j = idx & 31;
      float inv = powf(10000.0f, -(float)(2 * j) * (1.0f / 64.0f));
      float a = (float)p * inv;
      ct[idx] = cosf(a);
      st[idx] = sinf(a);
    }
  }
}

// ---------------- QKV GEMM (3-buf, counted vmcnt) + bias/RoPE epilogue; z==2 -> V^T ----------------
__global__ __launch_bounds__(256) void gemm_qkv(
    const unsigned short* __restrict__ X,
    const unsigned short* __restrict__ Wq, const unsigned short* __restrict__ Wk,
    const unsigned short* __restrict__ Wv,
    const float* __restrict__ bq, const float* __restrict__ bk, const float* __restrict__ bv,
    const float* __restrict__ ct, const float* __restrict__ st,
    unsigned short* __restrict__ Qo, unsigned short* __restrict__ Ko,
    unsigned short* __restrict__ VTo)   // V^T: [bh][d][s]
{
  __shared__ unsigned short LSH[24576];  // Al[3][4096] @0 | Bl[3][4096] @12288; T reuses first 16384
  const int z = blockIdx.z;
  const unsigned short* W = (z == 0) ? Wq : (z == 1) ? Wk : Wv;
  const float* bias = (z == 0) ? bq : (z == 1) ? bk : bv;
  const int tm = blockIdx.x, tn = blockIdx.y;
  const int t = threadIdx.x, w = t >> 6, l = t & 63;
  const int wm = w >> 1, wn = w & 1, g = l >> 4;

  f32x4 acc[4][4] = {};

  const int arow0 = tm * 128, brow0 = tn * 128;
  const int s0 = w * 2, s1 = w * 2 + 1;
  const int r0 = s0 * 16 + (l >> 2), r1 = s1 * 16 + (l >> 2);
  const int kc = (l & 3) * 8;

#define GSTAGE(buf, k0)                                                               \
  {                                                                                   \
    gload16(X + (long)(arow0 + r0) * HID + (k0) + kc, LSH + (buf) * 4096 + s0 * 512); \
    gload16(X + (long)(arow0 + r1) * HID + (k0) + kc, LSH + (buf) * 4096 + s1 * 512); \
    gload16(W + (long)(brow0 + r0) * HID + (k0) + kc, LSH + 12288 + (buf) * 4096 + s0 * 512); \
    gload16(W + (long)(brow0 + r1) * HID + (k0) + kc, LSH + 12288 + (buf) * 4096 + s1 * 512); \
  }

  GSTAGE(0, 0)
  GSTAGE(1, 32)
  asm volatile("s_waitcnt vmcnt(4)" ::: "memory");   // buf0 landed; buf1 in flight
  __builtin_amdgcn_s_barrier();
  int cur = 0, stg = 2;
  for (int k0 = 0; k0 < HID; k0 += 32) {
    if (k0 + 64 < HID) GSTAGE(stg, k0 + 64)
    bf16x8 af[4], bfr[4];
#pragma unroll
    for (int fm = 0; fm < 4; ++fm)
      af[fm] = *reinterpret_cast<const bf16x8*>(
          LSH + cur * 4096 + (wm * 64 + fm * 16 + (l & 15)) * 32 + g * 8);
#pragma unroll
    for (int fn = 0; fn < 4; ++fn)
      bfr[fn] = *reinterpret_cast<const bf16x8*>(
          LSH + 12288 + cur * 4096 + (wn * 64 + fn * 16 + (l & 15)) * 32 + g * 8);
    __builtin_amdgcn_s_setprio(1);
#pragma unroll
    for (int fm = 0; fm < 4; ++fm)
#pragma unroll
      for (int fn = 0; fn < 4; ++fn)
        acc[fm][fn] = __builtin_amdgcn_mfma_f32_16x16x32_bf16(af[fm], bfr[fn], acc[fm][fn], 0, 0, 0);
    __builtin_amdgcn_s_setprio(0);
    if (k0 + 64 < HID) {
      asm volatile("s_waitcnt vmcnt(4)" ::: "memory");   // next buf landed, newest stays in flight
    } else {
      asm volatile("s_waitcnt vmcnt(0)" ::: "memory");
    }
    __builtin_amdgcn_s_barrier();
    cur = (cur == 2) ? 0 : cur + 1;
    stg = (stg == 2) ? 0 : stg + 1;
  }
#undef GSTAGE

  const int colb = brow0 + wn * 64;
  float bsv[4];
#pragma unroll
  for (int fn = 0; fn < 4; ++fn) bsv[fn] = bias[colb + fn * 16 + (l & 15)];

  if (z == 2) {
    // ---- V^T epilogue: C-tile -> LDS transposed (XOR-swizzled) -> coalesced VT store
#pragma unroll
    for (int fm = 0; fm < 4; ++fm) {
      int tok = wm * 64 + fm * 16 + g * 4;
#pragma unroll
      for (int fn = 0; fn < 4; ++fn) {
        int col = wn * 64 + fn * 16 + (l & 15);
        unsigned int u0 = (unsigned int)bfc(acc[fm][fn][0] + bsv[fn]) |
                          ((unsigned int)bfc(acc[fm][fn][1] + bsv[fn]) << 16);
        unsigned int u1 = (unsigned int)bfc(acc[fm][fn][2] + bsv[fn]) |
                          ((unsigned int)bfc(acc[fm][fn][3] + bsv[fn]) << 16);
        uint2 uv; uv.x = u0; uv.y = u1;
        *reinterpret_cast<uint2*>(&LSH[col * 128 + (tok ^ ((col & 7) << 3))]) = uv;
      }
    }
    __syncthreads();
    const int bb = arow0 >> 11, stok = arow0 & (SEQ - 1);
#pragma unroll
    for (int p8 = 0; p8 < 8; ++p8) {
      int col = p8 * 16 + (t >> 4);          // 0..127
      int soff = (t & 15) * 8;
      uint4 v = *reinterpret_cast<const uint4*>(&LSH[col * 128 + (soff ^ ((col & 7) << 3))]);
      int hh = (brow0 + col) >> 6;
      int dd = col & 63;
      unsigned short* dst = VTo + ((long)(bb * NHEADS + hh) * HDIM + dd) * SEQ + stok + soff;
      *reinterpret_cast<uint4*>(dst) = v;
    }
    return;
  }

  // ---- Q/K epilogue: bias + RoPE (+0.125*log2e folded into Q), store [B][H][S][D]
  unsigned short* Out = (z == 0) ? Qo : Ko;
  const int h = colb >> 6;
#pragma unroll
  for (int fm = 0; fm < 4; ++fm) {
#pragma unroll
    for (int r = 0; r < 4; ++r) {
      int grow = arow0 + wm * 64 + fm * 16 + g * 4 + r;
      int b = grow >> 11, sidx = grow & (SEQ - 1);
      unsigned short* ob = Out + ((long)(b * NHEADS + h) * SEQ + sidx) * HDIM;
#pragma unroll
      for (int fn2 = 0; fn2 < 2; ++fn2) {
        int d1 = fn2 * 16 + (l & 15);               // 0..31
        float v1 = acc[fm][fn2][r] + bsv[fn2];
        float v2 = acc[fm][fn2 + 2][r] + bsv[fn2 + 2];
        float c = ct[sidx * 32 + d1], sn = st[sidx * 32 + d1];
        float o1 = v1 * c - v2 * sn;                // d
        float o2 = v2 * c + v1 * sn;                // d+32
        if (z == 0) { o1 *= 0.18033688f; o2 *= 0.18033688f; } // 0.125 * log2(e)
        ob[d1] = bfc(o1);
        ob[d1 + 32] = bfc(o2);
      }
    }
  }
}

// ---------------- flash attention R15: 2-wave blocks, 4 blocks/CU ----------------
// Block = 128 threads (2 waves x 32 q = 64 q). KVBLK=64, 32 tiles.
// K[2]/V[3] ring (40KB -> 4 blocks/CU); stage tile t+1 at iter start, drain at
// iter end (R13 pattern). 32x32 MFMA swapped QK^T, in-register P, ones-A row-sum.
__global__ __launch_bounds__(128, 2) void attn(
    const unsigned short* __restrict__ Qb,
    const unsigned short* __restrict__ Kb,
    const unsigned short* __restrict__ VTb,
    unsigned short* __restrict__ Ob)   // [NTOK][HID] bf16
{
  __shared__ unsigned short Kl[2][64 * 64];    // [key][d], swizzle ^((key&7)<<4)
  __shared__ unsigned short Vl[3][64 * 64];    // [d][key], swizzle ^((d&7)<<4)
  const int bh = blockIdx.x, qt = blockIdx.y;
  const int b = bh >> 4, h = bh & 15;
  const int t = threadIdx.x, w = t >> 6, l = t & 63;
  const long hb = (long)bh * SEQ * HDIM;
  const int hh = l >> 5;          // half-wave index
  const int swz = (l & 7) << 4;   // byte swizzle for row-reads (row&7 == l&7)

  // Q as B-operand: col=l&31 (q), k(d) = dc*16 + hh*8 + j
  const int q0 = qt * 64 + w * 32;
  bf16x8 qf[4];
#pragma unroll
  for (int dc = 0; dc < 4; ++dc)
    qf[dc] = *reinterpret_cast<const bf16x8*>(
        Qb + hb + (long)(q0 + (l & 31)) * HDIM + dc * 16 + hh * 8);

  f32x16 oacc[2] = {};           // O^T d-blocks; col=q=l&31
  f32x16 oaccE = {};             // every reg = row-sum of P for q=l&31
  const f32x16 FZ16 = {};

  // ones A-fragment (bf16 1.0 x8)
  u32x4 ou; ou[0] = 0x3F803F80u; ou[1] = 0x3F803F80u; ou[2] = 0x3F803F80u; ou[3] = 0x3F803F80u;
  const bf16x8 ones8 = __builtin_bit_cast(bf16x8, ou);

  // staging: wave w covers rows w*32 .. w*32+31 (4 calls of 8 rows each), for K and V
  const int srow = l >> 3;
  const int scol = (((l & 7) * 16) ^ ((l >> 3) << 4)) >> 1;
  const unsigned short* kp0 = Kb + hb + (long)(w * 32 + srow) * HDIM + scol;
  const unsigned short* vp0 = VTb + hb + (long)(w * 32 + srow) * SEQ + scol;

#define STAGE(kb_, vb_)                                                       \
  {                                                                           \
    _Pragma("unroll")                                                         \
    for (int c = 0; c < 4; ++c)                                               \
      gload16(kp0 + c * 8 * HDIM, (char*)Kl + (kb_) * 8192 + w * 4096 + c * 1024); \
    _Pragma("unroll")                                                         \
    for (int c = 0; c < 4; ++c)                                               \
      gload16(vp0 + c * 8 * SEQ, (char*)Vl + (vb_) * 8192 + w * 4096 + c * 1024);  \
    kp0 += 64 * HDIM; vp0 += 64;                                              \
  }

// S^T = K Q : sa[blk] covers keys 32blk..32blk+31 for this wave's 32 q
#define QK(kbuf)                                                                  \
  _Pragma("unroll")                                                               \
  for (int blk = 0; blk < 2; ++blk) {                                             \
    const char* kb_ = (char*)Kl + (kbuf) * 8192 + (32 * blk + (l & 31)) * 128;    \
    bf16x8 kf0 = *reinterpret_cast<const bf16x8*>(kb_ + ((0 * 32 + hh * 16) ^ swz)); \
    sa[blk] = MFMA32(kf0, qf[0], FZ16);                                           \
    bf16x8 kf1 = *reinterpret_cast<const bf16x8*>(kb_ + ((1 * 32 + hh * 16) ^ swz)); \
    sa[blk] = MFMA32(kf1, qf[1], sa[blk]);                                        \
    bf16x8 kf2 = *reinterpret_cast<const bf16x8*>(kb_ + ((2 * 32 + hh * 16) ^ swz)); \
    sa[blk] = MFMA32(kf2, qf[2], sa[blk]);                                        \
    bf16x8 kf3 = *reinterpret_cast<const bf16x8*>(kb_ + ((3 * 32 + hh * 16) ^ swz)); \
    sa[blk] = MFMA32(kf3, qf[3], sa[blk]);                                        \
  }

#define SOFTEXP                                                                   \
  _Pragma("unroll")                                                               \
  for (int blk = 0; blk < 2; ++blk)                                               \
    _Pragma("unroll")                                                             \
    for (int r = 0; r < 16; ++r) sa[blk][r] = EXP2(sa[blk][r]);

// build PV B-frags in-register: pB[2blk+c] = keys 16(2blk+c)+8h+{0..7} for q=l&31
#define PBUILD                                                                    \
  _Pragma("unroll")                                                               \
  for (int blk = 0; blk < 2; ++blk) {                                             \
    unsigned int w0a = pk(sa[blk][0], sa[blk][1]);                                \
    unsigned int w1a = pk(sa[blk][2], sa[blk][3]);                                \
    unsigned int w0b = pk(sa[blk][4], sa[blk][5]);                                \
    unsigned int w1b = pk(sa[blk][6], sa[blk][7]);                                \
    unsigned int w0c = pk(sa[blk][8], sa[blk][9]);                                \
    unsigned int w1c = pk(sa[blk][10], sa[blk][11]);                              \
    unsigned int w0d = pk(sa[blk][12], sa[blk][13]);                              \
    unsigned int w1d = pk(sa[blk][14], sa[blk][15]);                              \
    plswap(w0a, w0b); plswap(w1a, w1b);                                           \
    plswap(w0c, w0d); plswap(w1c, w1d);                                           \
    u32x4 f0; f0[0] = w0a; f0[1] = w1a; f0[2] = w0b; f0[3] = w1b;                 \
    u32x4 f1; f1[0] = w0c; f1[1] = w1c; f1[2] = w0d; f1[3] = w1d;                 \
    pB[2 * blk + 0] = __builtin_bit_cast(bf16x8, f0);                             \
    pB[2 * blk + 1] = __builtin_bit_cast(bf16x8, f1);                             \
  }

// O^T += V^T P ; oaccE += 1*P (row-sum)
#define PVSTEP(vbuf)                                                              \
  _Pragma("unroll")                                                               \
  for (int db = 0; db < 2; ++db) {                                                \
    const char* vb_ = (char*)Vl + (vbuf) * 8192 + (32 * db + (l & 31)) * 128;     \
    _Pragma("unroll")                                                             \
    for (int kc = 0; kc < 4; ++kc) {                                              \
      bf16x8 vf = *reinterpret_cast<const bf16x8*>(vb_ + ((kc * 32 + hh * 16) ^ swz)); \
      oacc[db] = MFMA32(vf, pB[kc], oacc[db]);                                    \
    }                                                                             \
  }                                                                               \
  _Pragma("unroll")                                                               \
  for (int kc = 0; kc < 4; ++kc) oaccE = MFMA32(ones8, pB[kc], oaccE);

#define ITER(KB, VR, VW)                                   \
  {                                                        \
    STAGE((KB) ^ 1, VW)                                    \
    __builtin_amdgcn_s_setprio(1);                         \
    QK(KB)                                                 \
    PVSTEP(VR)                                             \
    __builtin_amdgcn_s_setprio(0);                         \
    SOFTEXP                                                \
    PBUILD                                                 \
    asm volatile("s_waitcnt vmcnt(0)" ::: "memory");       \
    __builtin_amdgcn_s_barrier();                          \
  }
#define ITER_NOSTAGE(KB, VR)                               \
  {                                                        \
    __builtin_amdgcn_s_setprio(1);                         \
    QK(KB)                                                 \
    PVSTEP(VR)                                             \
    __builtin_amdgcn_s_setprio(0);                         \
    SOFTEXP                                                \
    PBUILD                                                 \
  }

  f32x16 sa[2];
  bf16x8 pB[4];

  // prologue: stage tile 0 into K[0],V[0]
  STAGE(1 ^ 1, 0)   // K buf 0
  asm volatile("s_waitcnt vmcnt(0)" ::: "memory");
  __builtin_amdgcn_s_barrier();

  // peeled t=0: stage tile 1 -> K[1],V[1]; QK(0); exp2+PBUILD; no PV yet
  STAGE(0 ^ 1, 1)   // K buf 1
  __builtin_amdgcn_s_setprio(1);
  QK(0)
  __builtin_amdgcn_s_setprio(0);
  SOFTEXP
  PBUILD
  asm volatile("s_waitcnt vmcnt(0)" ::: "memory");
  __builtin_amdgcn_s_barrier();

  // main: t = 1..30, (KB=t&1, VR=(t-1)%3, VW=(t+1)%3), period 6, 5 groups
  for (int m = 0; m < 5; ++m) {
    ITER(1, 0, 2)
    ITER(0, 1, 0)
    ITER(1, 2, 1)
    ITER(0, 0, 2)
    ITER(1, 1, 0)
    ITER(0, 2, 1)
  }
  ITER_NOSTAGE(1, 0)   // t=31 (tile 31 staged at t=30 into V[1]/K[1]... K[0]? 31&1=1 -> K[1]; staged at t=30: KB=0 -> stage K[1] ✓)

  // epilogue: PV of tile 31 (P in pB, V in Vl[31 % 3 = 1])
  __builtin_amdgcn_s_setprio(1);
  PVSTEP(1)
  __builtin_amdgcn_s_setprio(0);

#undef STAGE
#undef QK
#undef SOFTEXP
#undef PBUILD
#undef PVSTEP
#undef ITER
#undef ITER_NOSTAGE

  // ---- normalize + store O^T (lane owns q = q0+(l&31); d = (r&3)+8(r>>2)+4hh+32db)
  {
    float inv = 1.0f / oaccE[0];
    int q = q0 + (l & 31);
    unsigned short* op = Ob + (long)(b * SEQ + q) * HID + h * HDIM;
#pragma unroll
    for (int db = 0; db < 2; ++db)
#pragma unroll
      for (int a = 0; a < 4; ++a) {
        int d = 8 * a + 4 * hh + 32 * db;
        unsigned int lo = pk(oacc[db][4 * a + 0] * inv, oacc[db][4 * a + 1] * inv);
        unsigned int hi2 = pk(oacc[db][4 * a + 2] * inv, oacc[db][4 * a + 3] * inv);
        uint2 uv; uv.x = lo; uv.y = hi2;
        *reinterpret_cast<uint2*>(op + d) = uv;
      }
  }
}

// ---------------- output projection (3-buf counted vmcnt, 128x64 tile): fp32 out ----------------
__global__ __launch_bounds__(256) void gemm_o(
    const unsigned short* __restrict__ A,
    const unsigned short* __restrict__ W,
    const float* __restrict__ bias,
    float* __restrict__ Out)
{
  __shared__ unsigned short Al[3][128 * 32];
  __shared__ unsigned short Bl[3][64 * 32];
  const int tm = blockIdx.x, tn = blockIdx.y;
  const int t = threadIdx.x, w = t >> 6, l = t & 63;
  const int wm = w >> 1, wn = w & 1;

  f32x4 acc[4][2] = {};
  const int arow0 = tm * 128, brow0 = tn * 64;
  const int s0 = w * 2, s1 = w * 2 + 1;
  const int r0 = s0 * 16 + (l >> 2), r1 = s1 * 16 + (l >> 2);
  const int rb = w * 16 + (l >> 2);
  const int kc = (l & 3) * 8;

#define GSTAGE(buf, k0)                                                       \
  {                                                                           \
    gload16(A + (long)(arow0 + r0) * HID + (k0) + kc, Al[buf] + s0 * 512);    \
    gload16(A + (long)(arow0 + r1) * HID + (k0) + kc, Al[buf] + s1 * 512);    \
    gload16(W + (long)(brow0 + rb) * HID + (k0) + kc, Bl[buf] + w * 512);     \
  }

  GSTAGE(0, 0)
  GSTAGE(1, 32)
  asm volatile("s_waitcnt vmcnt(3)" ::: "memory");
  __builtin_amdgcn_s_barrier();
  int cur = 0, stg = 2;
  for (int k0 = 0; k0 < HID; k0 += 32) {
    if (k0 + 64 < HID) GSTAGE(stg, k0 + 64)
    bf16x8 af[4], bfr[2];
#pragma unroll
    for (int fm = 0; fm < 4; ++fm)
      af[fm] = *reinterpret_cast<const bf16x8*>(Al[cur] + (wm * 64 + fm * 16 + (l & 15)) * 32 + (l >> 4) * 8);
#pragma unroll
    for (int fn = 0; fn < 2; ++fn)
      bfr[fn] = *reinterpret_cast<const bf16x8*>(Bl[cur] + (wn * 32 + fn * 16 + (l & 15)) * 32 + (l >> 4) * 8);
    __builtin_amdgcn_s_setprio(1);
#pragma unroll
    for (int fm = 0; fm < 4; ++fm)
#pragma unroll
      for (int fn = 0; fn < 2; ++fn)
        acc[fm][fn] = __builtin_amdgcn_mfma_f32_16x16x32_bf16(af[fm], bfr[fn], acc[fm][fn], 0, 0, 0);
    __builtin_amdgcn_s_setprio(0);
    if (k0 + 64 < HID) {
      asm volatile("s_waitcnt vmcnt(3)" ::: "memory");
    } else {
      asm volatile("s_waitcnt vmcnt(0)" ::: "memory");
    }
    __builtin_amdgcn_s_barrier();
    cur = (cur == 2) ? 0 : cur + 1;
    stg = (stg == 2) ? 0 : stg + 1;
  }
#undef GSTAGE

  const int colb = brow0 + wn * 32;
  float bsv[2];
#pragma unroll
  for (int fn = 0; fn < 2; ++fn) bsv[fn] = bias[colb + fn * 16 + (l & 15)];
#pragma unroll
  for (int fm = 0; fm < 4; ++fm)
#pragma unroll
    for (int r = 0; r < 4; ++r) {
      int grow = arow0 + wm * 64 + fm * 16 + (l >> 4) * 4 + r;
#pragma unroll
      for (int fn = 0; fn < 2; ++fn)
        Out[(long)grow * HID + colb + fn * 16 + (l & 15)] = acc[fm][fn][r] + bsv[fn];
    }
}

extern "C" void kernel_launch(void* const* d_in, const int* in_sizes, int n_in,
                              void* d_out, int out_size, void* d_ws, size_t ws_size,
                              hipStream_t stream) {
  const float* x  = (const float*)d_in[0];
  const float* qw = (const float*)d_in[1];
  const float* qb = (const float*)d_in[2];
  const float* kw = (const float*)d_in[3];
  const float* kb = (const float*)d_in[4];
  const float* vw = (const float*)d_in[5];
  const float* vb = (const float*)d_in[6];
  const float* ow = (const float*)d_in[7];
  const float* ob = (const float*)d_in[8];
  float* out = (float*)d_out;

  char* p = (char*)d_ws;
  unsigned short* xb  = (unsigned short*)p; p += (size_t)NTOK * HID * 2;
  unsigned short* wqb = (unsigned short*)p; p += (size_t)HID * HID * 2;
  unsigned short* wkb = (unsigned short*)p; p += (size_t)HID * HID * 2;
  unsigned short* wvb = (unsigned short*)p; p += (size_t)HID * HID * 2;
  unsigned short* wob = (unsigned short*)p; p += (size_t)HID * HID * 2;
  unsigned short* Qb  = (unsigned short*)p; p += (size_t)NTOK * HID * 2;
  unsigned short* Kb  = (unsigned short*)p; p += (size_t)NTOK * HID * 2;
  unsigned short* VTb = (unsigned short*)p; p += (size_t)NTOK * HID * 2;
  float* ct = (float*)p; p += (size_t)SEQ * 32 * 4;
  float* st = (float*)p; p += (size_t)SEQ * 32 * 4;
  unsigned short* Ab  = xb;   // xb dead after gemm_qkv; reuse for attn output

  const int XN = NTOK * HID / 8, WN = HID * HID / 8;
  const int prep_threads = XN + 4 * WN + SEQ * 32;
  prep<<<dim3((prep_threads + 255) / 256), 256, 0, stream>>>(
      x, qw, kw, vw, ow, xb, wqb, wkb, wvb, wob, ct, st);

  gemm_qkv<<<dim3(NTOK / 128, HID / 128, 3), 256, 0, stream>>>(
      xb, wqb, wkb, wvb, qb, kb, vb, ct, st, Qb, Kb, VTb);

  attn<<<dim3(BATCH * NHEADS, SEQ / 64), 128, 0, stream>>>(Qb, Kb, VTb, Ab);

  gemm_o<<<dim3(NTOK / 128, HID / 64), 256, 0, stream>>>(Ab, wob, ob, out);
}

// Round 16
// 104.358 us; speedup vs baseline: 1.1165x; 1.1165x over previous
//
#include <hip/hip_runtime.h>
#include <hip/hip_bf16.h>

// MultiHeadAttention: x[2,2048,1024] fp32 -> QKV proj + RoPE + softmax attn + O proj
// R16: GEMMs moved to BK=64 (half the barrier-fenced K-iterations), 128B-row
// swizzled LDS tiles (attn-verified format). attn reverted to R13 (best: 49.4us).

#define SEQ    2048
#define BATCH  2
#define NHEADS 16
#define HDIM   64
#define HID    1024
#define NTOK   (BATCH*SEQ)   // 4096

typedef __bf16 bf16x8 __attribute__((ext_vector_type(8)));
typedef float  f32x4  __attribute__((ext_vector_type(4)));
typedef float  f32x16 __attribute__((ext_vector_type(16)));
typedef unsigned short u16x8 __attribute__((ext_vector_type(8)));
typedef unsigned int   u32x4 __attribute__((ext_vector_type(4)));

__device__ __forceinline__ unsigned short bfc(float x) {
  return __builtin_bit_cast(unsigned short, (__bf16)x);   // native v_cvt (RNE)
}
__device__ __forceinline__ unsigned int pk(float lo, float hi) {
  return (unsigned int)bfc(lo) | ((unsigned int)bfc(hi) << 16);
}
// swap upper 32 lanes of a with lower 32 lanes of b (gfx950)
__device__ __forceinline__ void plswap(unsigned int& a, unsigned int& b) {
  asm volatile("v_permlane32_swap_b32 %0, %1" : "+v"(a), "+v"(b));
}
#define EXP2(x) __builtin_amdgcn_exp2f(x)
#define MFMA32(a, b, c) __builtin_amdgcn_mfma_f32_32x32x16_bf16(a, b, c, 0, 0, 0)

// async global->LDS, 16B per lane. dest = wave-uniform base (+ lane*16 by HW).
__device__ __forceinline__ void gload16(const void* gptr, void* ldsptr) {
  typedef __attribute__((address_space(3))) unsigned int as3_uint;
  typedef const __attribute__((address_space(1))) unsigned int as1_uint;
  __builtin_amdgcn_global_load_lds(
      (as1_uint*)(unsigned long long)gptr,
      (as3_uint*)(unsigned int)(unsigned long long)ldsptr,
      16, 0, 0);
}

__device__ __forceinline__ void cvt8(const float* __restrict__ s,
                                     unsigned short* __restrict__ d, int i) {
  float4 a = *reinterpret_cast<const float4*>(s + i);
  float4 b = *reinterpret_cast<const float4*>(s + i + 4);
  u16x8 o;
  o[0] = bfc(a.x); o[1] = bfc(a.y); o[2] = bfc(a.z); o[3] = bfc(a.w);
  o[4] = bfc(b.x); o[5] = bfc(b.y); o[6] = bfc(b.z); o[7] = bfc(b.w);
  *reinterpret_cast<u16x8*>(d + i) = o;
}

// ---------------- prep: all converts + rope tables in ONE launch ----------------
__global__ __launch_bounds__(256) void prep(
    const float* __restrict__ x,
    const float* __restrict__ qw, const float* __restrict__ kw,
    const float* __restrict__ vw, const float* __restrict__ ow,
    unsigned short* __restrict__ xb,
    unsigned short* __restrict__ wqb, unsigned short* __restrict__ wkb,
    unsigned short* __restrict__ wvb, unsigned short* __restrict__ wob,
    float* __restrict__ ct, float* __restrict__ st)
{
  const int XN = NTOK * HID / 8;   // 524288
  const int WN = HID * HID / 8;    // 131072 (pow2)
  int tid = blockIdx.x * 256 + threadIdx.x;
  if (tid < XN) {
    cvt8(x, xb, tid * 8);
  } else if (tid < XN + 4 * WN) {
    int r = tid - XN;
    int which = r >> 17;                 // / 131072
    int i = (r & (WN - 1)) * 8;
    const float* s = (which == 0) ? qw : (which == 1) ? kw : (which == 2) ? vw : ow;
    unsigned short* d = (which == 0) ? wqb : (which == 1) ? wkb : (which == 2) ? wvb : wob;
    cvt8(s, d, i);
  } else {
    int idx = tid - (XN + 4 * WN);
    if (idx < SEQ * 32) {
      int p = idx >> 5, j = idx & 31;
      float inv = powf(10000.0f, -(float)(2 * j) * (1.0f / 64.0f));
      float a = (float)p * inv;
      ct[idx] = cosf(a);
      st[idx] = sinf(a);
    }
  }
}

// ---------------- QKV GEMM: BK=64 dbuf, 128B-row swizzled tiles ----------------
__global__ __launch_bounds__(256, 2) void gemm_qkv(
    const unsigned short* __restrict__ X,
    const unsigned short* __restrict__ Wq, const unsigned short* __restrict__ Wk,
    const unsigned short* __restrict__ Wv,
    const float* __restrict__ bq, const float* __restrict__ bk, const float* __restrict__ bv,
    const float* __restrict__ ct, const float* __restrict__ st,
    unsigned short* __restrict__ Qo, unsigned short* __restrict__ Ko,
    unsigned short* __restrict__ VTo)   // V^T: [bh][d][s]
{
  __shared__ unsigned short LSH[32768];  // A[2] @0 (2x8192 shorts) | B[2] @16384; 64KB
  const int z = blockIdx.z;
  const unsigned short* W = (z == 0) ? Wq : (z == 1) ? Wk : Wv;
  const float* bias = (z == 0) ? bq : (z == 1) ? bk : bv;
  const int tm = blockIdx.x, tn = blockIdx.y;
  const int t = threadIdx.x, w = t >> 6, l = t & 63;
  const int wm = w >> 1, wn = w & 1, g = l >> 4;
  const int swz = (l & 7) << 4;

  f32x4 acc[4][4] = {};

  const int arow0 = tm * 128, brow0 = tn * 128;
  // staging coords: wave w covers rows w*32..w*32+31, 4 calls of 8 rows
  const int srow = l >> 3;
  const int scol = (((l & 7) * 16) ^ ((l >> 3) << 4)) >> 1;   // pre-swizzled elem col

#define GSTAGE(buf, k0)                                                             \
  {                                                                                 \
    _Pragma("unroll")                                                               \
    for (int c = 0; c < 4; ++c)                                                     \
      gload16(X + (long)(arow0 + w * 32 + c * 8 + srow) * HID + (k0) + scol,        \
              (char*)LSH + (buf) * 16384 + w * 4096 + c * 1024);                    \
    _Pragma("unroll")                                                               \
    for (int c = 0; c < 4; ++c)                                                     \
      gload16(W + (long)(brow0 + w * 32 + c * 8 + srow) * HID + (k0) + scol,        \
              (char*)LSH + 32768 + (buf) * 16384 + w * 4096 + c * 1024);            \
  }

  GSTAGE(0, 0)
  asm volatile("s_waitcnt vmcnt(0)" ::: "memory");
  __builtin_amdgcn_s_barrier();
  int cur = 0;
  for (int k0 = 0; k0 < HID; k0 += 64) {
    if (k0 + 64 < HID) GSTAGE(cur ^ 1, k0 + 64)
#pragma unroll
    for (int kk = 0; kk < 2; ++kk) {
      bf16x8 af[4], bfr[4];
#pragma unroll
      for (int fm = 0; fm < 4; ++fm) {
        int row = wm * 64 + fm * 16 + (l & 15);
        af[fm] = *reinterpret_cast<const bf16x8*>(
            (char*)LSH + cur * 16384 + row * 128 + ((kk * 64 + g * 16) ^ swz));
      }
#pragma unroll
      for (int fn = 0; fn < 4; ++fn) {
        int row = wn * 64 + fn * 16 + (l & 15);
        bfr[fn] = *reinterpret_cast<const bf16x8*>(
            (char*)LSH + 32768 + cur * 16384 + row * 128 + ((kk * 64 + g * 16) ^ swz));
      }
      __builtin_amdgcn_s_setprio(1);
#pragma unroll
      for (int fm = 0; fm < 4; ++fm)
#pragma unroll
        for (int fn = 0; fn < 4; ++fn)
          acc[fm][fn] = __builtin_amdgcn_mfma_f32_16x16x32_bf16(af[fm], bfr[fn], acc[fm][fn], 0, 0, 0);
      __builtin_amdgcn_s_setprio(0);
    }
    asm volatile("s_waitcnt vmcnt(0)" ::: "memory");
    __builtin_amdgcn_s_barrier();
    cur ^= 1;
  }
#undef GSTAGE

  const int colb = brow0 + wn * 64;
  float bsv[4];
#pragma unroll
  for (int fn = 0; fn < 4; ++fn) bsv[fn] = bias[colb + fn * 16 + (l & 15)];

  if (z == 2) {
    // ---- V^T epilogue: C-tile -> LDS transposed (XOR-swizzled) -> coalesced VT store
#pragma unroll
    for (int fm = 0; fm < 4; ++fm) {
      int tok = wm * 64 + fm * 16 + g * 4;
#pragma unroll
      for (int fn = 0; fn < 4; ++fn) {
        int col = wn * 64 + fn * 16 + (l & 15);
        unsigned int u0 = (unsigned int)bfc(acc[fm][fn][0] + bsv[fn]) |
                          ((unsigned int)bfc(acc[fm][fn][1] + bsv[fn]) << 16);
        unsigned int u1 = (unsigned int)bfc(acc[fm][fn][2] + bsv[fn]) |
                          ((unsigned int)bfc(acc[fm][fn][3] + bsv[fn]) << 16);
        uint2 uv; uv.x = u0; uv.y = u1;
        *reinterpret_cast<uint2*>(&LSH[col * 128 + (tok ^ ((col & 7) << 3))]) = uv;
      }
    }
    __syncthreads();
    const int bb = arow0 >> 11, stok = arow0 & (SEQ - 1);
#pragma unroll
    for (int p8 = 0; p8 < 8; ++p8) {
      int col = p8 * 16 + (t >> 4);          // 0..127
      int soff = (t & 15) * 8;
      uint4 v = *reinterpret_cast<const uint4*>(&LSH[col * 128 + (soff ^ ((col & 7) << 3))]);
      int hh = (brow0 + col) >> 6;
      int dd = col & 63;
      unsigned short* dst = VTo + ((long)(bb * NHEADS + hh) * HDIM + dd) * SEQ + stok + soff;
      *reinterpret_cast<uint4*>(dst) = v;
    }
    return;
  }

  // ---- Q/K epilogue: bias + RoPE (+0.125*log2e folded into Q), store [B][H][S][D]
  unsigned short* Out = (z == 0) ? Qo : Ko;
  const int h = colb >> 6;
#pragma unroll
  for (int fm = 0; fm < 4; ++fm) {
#pragma unroll
    for (int r = 0; r < 4; ++r) {
      int grow = arow0 + wm * 64 + fm * 16 + g * 4 + r;
      int b = grow >> 11, sidx = grow & (SEQ - 1);
      unsigned short* ob = Out + ((long)(b * NHEADS + h) * SEQ + sidx) * HDIM;
#pragma unroll
      for (int fn2 = 0; fn2 < 2; ++fn2) {
        int d1 = fn2 * 16 + (l & 15);               // 0..31
        float v1 = acc[fm][fn2][r] + bsv[fn2];
        float v2 = acc[fm][fn2 + 2][r] + bsv[fn2 + 2];
        float c = ct[sidx * 32 + d1], sn = st[sidx * 32 + d1];
        float o1 = v1 * c - v2 * sn;                // d
        float o2 = v2 * c + v1 * sn;                // d+32
        if (z == 0) { o1 *= 0.18033688f; o2 *= 0.18033688f; } // 0.125 * log2(e)
        ob[d1] = bfc(o1);
        ob[d1 + 32] = bfc(o2);
      }
    }
  }
}

// ---------------- flash attention (R13, best measured): KVBLK=128, 16 tiles ----------------
__global__ __launch_bounds__(256, 2) void attn(
    const unsigned short* __restrict__ Qb,
    const unsigned short* __restrict__ Kb,
    const unsigned short* __restrict__ VTb,
    unsigned short* __restrict__ Ob)   // [NTOK][HID] bf16
{
  __shared__ unsigned short Kl[2][128 * 64];   // [key][d], swizzle ^((key&7)<<4)
  __shared__ unsigned short Vl[3][8192];       // [half][d][key64], swizzle ^((d&7)<<4)
  const int bh = blockIdx.x, qt = blockIdx.y;
  const int b = bh >> 4, h = bh & 15;
  const int t = threadIdx.x, w = t >> 6, l = t & 63;
  const long hb = (long)bh * SEQ * HDIM;
  const int hh = l >> 5;          // half-wave index
  const int swz = (l & 7) << 4;   // byte swizzle for row-reads (row&7 == l&7)

  // Q as B-operand: col=l&31 (q), k(d) = dc*16 + hh*8 + j
  const int q0 = qt * 128 + w * 32;
  bf16x8 qf[4];
#pragma unroll
  for (int dc = 0; dc < 4; ++dc)
    qf[dc] = *reinterpret_cast<const bf16x8*>(
        Qb + hb + (long)(q0 + (l & 31)) * HDIM + dc * 16 + hh * 8);

  f32x16 oacc[2] = {};           // O^T d-blocks; col=q=l&31
  f32x16 oaccE = {};             // every reg = row-sum of P for q=l&31
  const f32x16 FZ16 = {};

  // ones A-fragment (bf16 1.0 x8)
  u32x4 ou; ou[0] = 0x3F803F80u; ou[1] = 0x3F803F80u; ou[2] = 0x3F803F80u; ou[3] = 0x3F803F80u;
  const bf16x8 ones8 = __builtin_bit_cast(bf16x8, ou);

  // staging pointers (advance by one 128-key tile per STAGE)
  const int srow = l >> 3;
  const int scol = (((l & 7) * 16) ^ ((l >> 3) << 4)) >> 1;
  const unsigned short* kp0 = Kb + hb + (long)(w * 32 + srow) * HDIM + scol;
  const unsigned short* kp1 = kp0 + 8 * HDIM;
  const unsigned short* kp2 = kp0 + 16 * HDIM;
  const unsigned short* kp3 = kp0 + 24 * HDIM;
  const unsigned short* vp0 = VTb + hb + (long)(w * 16 + srow) * SEQ + scol;   // half0 rows w16..+7
  const unsigned short* vp1 = vp0 + 8 * SEQ;                                   // half0 rows +8
  const unsigned short* vp2 = vp0 + 64;                                        // half1
  const unsigned short* vp3 = vp1 + 64;

#define STAGE(kbuf, vbuf)                                                   \
  {                                                                         \
    gload16(kp0, (char*)Kl + (kbuf) * 16384 + w * 4096);                    \
    gload16(kp1, (char*)Kl + (kbuf) * 16384 + w * 4096 + 1024);             \
    gload16(kp2, (char*)Kl + (kbuf) * 16384 + w * 4096 + 2048);             \
    gload16(kp3, (char*)Kl + (kbuf) * 16384 + w * 4096 + 3072);             \
    gload16(vp0, (char*)Vl + (vbuf) * 16384 + w * 2048);                    \
    gload16(vp1, (char*)Vl + (vbuf) * 16384 + w * 2048 + 1024);             \
    gload16(vp2, (char*)Vl + (vbuf) * 16384 + 8192 + w * 2048);             \
    gload16(vp3, (char*)Vl + (vbuf) * 16384 + 8192 + w * 2048 + 1024);      \
    kp0 += 128 * HDIM; kp1 += 128 * HDIM; kp2 += 128 * HDIM; kp3 += 128 * HDIM; \
    vp0 += 128; vp1 += 128; vp2 += 128; vp3 += 128;                         \
  }

// S^T = K Q : sa[blk] covers keys 32blk..32blk+31 for this wave's 32 q
#define QK(kbuf)                                                                  \
  _Pragma("unroll")                                                               \
  for (int blk = 0; blk < 4; ++blk) {                                             \
    const char* kb_ = (char*)Kl + (kbuf) * 16384 + (32 * blk + (l & 31)) * 128;   \
    bf16x8 kf0 = *reinterpret_cast<const bf16x8*>(kb_ + ((0 * 32 + hh * 16) ^ swz)); \
    sa[blk] = MFMA32(kf0, qf[0], FZ16);                                           \
    bf16x8 kf1 = *reinterpret_cast<const bf16x8*>(kb_ + ((1 * 32 + hh * 16) ^ swz)); \
    sa[blk] = MFMA32(kf1, qf[1], sa[blk]);                                        \
    bf16x8 kf2 = *reinterpret_cast<const bf16x8*>(kb_ + ((2 * 32 + hh * 16) ^ swz)); \
    sa[blk] = MFMA32(kf2, qf[2], sa[blk]);                                        \
    bf16x8 kf3 = *reinterpret_cast<const bf16x8*>(kb_ + ((3 * 32 + hh * 16) ^ swz)); \
    sa[blk] = MFMA32(kf3, qf[3], sa[blk]);                                        \
  }

#define SOFTEXP                                                                   \
  _Pragma("unroll")                                                               \
  for (int blk = 0; blk < 4; ++blk)                                               \
    _Pragma("unroll")                                                             \
    for (int r = 0; r < 16; ++r) sa[blk][r] = EXP2(sa[blk][r]);

// build PV B-frags in-register: pB[2blk+c] = keys 16(2blk+c)+8h+{0..7} for q=l&31
#define PBUILD                                                                    \
  _Pragma("unroll")                                                               \
  for (int blk = 0; blk < 4; ++blk) {                                             \
    unsigned int w0a = pk(sa[blk][0], sa[blk][1]);                                \
    unsigned int w1a = pk(sa[blk][2], sa[blk][3]);                                \
    unsigned int w0b = pk(sa[blk][4], sa[blk][5]);                                \
    unsigned int w1b = pk(sa[blk][6], sa[blk][7]);                                \
    unsigned int w0c = pk(sa[blk][8], sa[blk][9]);                                \
    unsigned int w1c = pk(sa[blk][10], sa[blk][11]);                              \
    unsigned int w0d = pk(sa[blk][12], sa[blk][13]);                              \
    unsigned int w1d = pk(sa[blk][14], sa[blk][15]);                              \
    plswap(w0a, w0b); plswap(w1a, w1b);                                           \
    plswap(w0c, w0d); plswap(w1c, w1d);                                           \
    u32x4 f0; f0[0] = w0a; f0[1] = w1a; f0[2] = w0b; f0[3] = w1b;                 \
    u32x4 f1; f1[0] = w0c; f1[1] = w1c; f1[2] = w0d; f1[3] = w1d;                 \
    pB[2 * blk + 0] = __builtin_bit_cast(bf16x8, f0);                             \
    pB[2 * blk + 1] = __builtin_bit_cast(bf16x8, f1);                             \
  }

// O^T += V^T P ; oaccE += 1*P (row-sum). kc 0..7 over 128 keys; half = kc>>2.
#define PVSTEP(vbuf)                                                              \
  _Pragma("unroll")                                                               \
  for (int db = 0; db < 2; ++db) {                                                \
    _Pragma("unroll")                                                             \
    for (int kc = 0; kc < 8; ++kc) {                                              \
      const char* vb_ = (char*)Vl + (vbuf) * 16384 + (kc >> 2) * 8192 +           \
                        (32 * db + (l & 31)) * 128 + (((kc & 3) * 32 + hh * 16) ^ swz); \
      bf16x8 vf = *reinterpret_cast<const bf16x8*>(vb_);                          \
      oacc[db] = MFMA32(vf, pB[kc], oacc[db]);                                    \
    }                                                                             \
  }                                                                               \
  _Pragma("unroll")                                                               \
  for (int kc = 0; kc < 8; ++kc) oaccE = MFMA32(ones8, pB[kc], oaccE);

#define ITER(KB, VR, VW)                                   \
  {                                                        \
    STAGE(KB ^ 1, VW)                                      \
    __builtin_amdgcn_s_setprio(1);                         \
    QK(KB)                                                 \
    PVSTEP(VR)                                             \
    __builtin_amdgcn_s_setprio(0);                         \
    SOFTEXP                                                \
    PBUILD                                                 \
    asm volatile("s_waitcnt vmcnt(0)" ::: "memory");       \
    __builtin_amdgcn_s_barrier();                          \
  }
#define ITER_NOSTAGE(KB, VR)                               \
  {                                                        \
    __builtin_amdgcn_s_setprio(1);                         \
    QK(KB)                                                 \
    PVSTEP(VR)                                             \
    __builtin_amdgcn_s_setprio(0);                         \
    SOFTEXP                                                \
    PBUILD                                                 \
    asm volatile("s_waitcnt vmcnt(0)" ::: "memory");       \
    __builtin_amdgcn_s_barrier();                          \
  }

  f32x16 sa[4];
  bf16x8 pB[8];

  // prologue: stage tile 0 into K[0],V[0]
  STAGE(0, 0)
  asm volatile("s_waitcnt vmcnt(0)" ::: "memory");
  __builtin_amdgcn_s_barrier();

  // peeled t=0: stage tile 1 -> K[1],V[1]; QK(0); exp2+PBUILD; no PV yet
  STAGE(1, 1)
  __builtin_amdgcn_s_setprio(1);
  QK(0)
  __builtin_amdgcn_s_setprio(0);
  SOFTEXP
  PBUILD
  asm volatile("s_waitcnt vmcnt(0)" ::: "memory");
  __builtin_amdgcn_s_barrier();

  // main: t=1..14 with (KB=t&1, VR=(t-1)%3, VW=(t+1)%3); period 6
  for (int m = 0; m < 2; ++m) {
    ITER(1, 0, 2)
    ITER(0, 1, 0)
    ITER(1, 2, 1)
    ITER(0, 0, 2)
    ITER(1, 1, 0)
    ITER(0, 2, 1)
  }
  ITER(1, 0, 2)        // t=13
  ITER(0, 1, 0)        // t=14 (stages tile 15 -> V[0])
  ITER_NOSTAGE(1, 2)   // t=15 (QK(15), PV(14))

  // epilogue: PV of tile 15 (P in pB, V in Vl[0])
  __builtin_amdgcn_s_setprio(1);
  PVSTEP(0)
  __builtin_amdgcn_s_setprio(0);

#undef STAGE
#undef QK
#undef SOFTEXP
#undef PBUILD
#undef PVSTEP
#undef ITER
#undef ITER_NOSTAGE

  // ---- normalize + store O^T (lane owns q = q0+(l&31); d = (r&3)+8(r>>2)+4hh+32db)
  {
    float inv = 1.0f / oaccE[0];
    int q = q0 + (l & 31);
    unsigned short* op = Ob + (long)(b * SEQ + q) * HID + h * HDIM;
#pragma unroll
    for (int db = 0; db < 2; ++db)
#pragma unroll
      for (int a = 0; a < 4; ++a) {
        int d = 8 * a + 4 * hh + 32 * db;
        unsigned int lo = pk(oacc[db][4 * a + 0] * inv, oacc[db][4 * a + 1] * inv);
        unsigned int hi2 = pk(oacc[db][4 * a + 2] * inv, oacc[db][4 * a + 3] * inv);
        uint2 uv; uv.x = lo; uv.y = hi2;
        *reinterpret_cast<uint2*>(op + d) = uv;
      }
  }
}

// ---------------- output projection: BK=64 dbuf, 128x64 tile ----------------
__global__ __launch_bounds__(256, 3) void gemm_o(
    const unsigned short* __restrict__ A,
    const unsigned short* __restrict__ W,
    const float* __restrict__ bias,
    float* __restrict__ Out)
{
  __shared__ unsigned short Al[2][128 * 64];   // 2x16KB, 128B rows swizzled
  __shared__ unsigned short Bl[2][64 * 64];    // 2x8KB
  const int tm = blockIdx.x, tn = blockIdx.y;
  const int t = threadIdx.x, w = t >> 6, l = t & 63;
  const int wm = w >> 1, wn = w & 1, g = l >> 4;
  const int swz = (l & 7) << 4;

  f32x4 acc[4][2] = {};
  const int arow0 = tm * 128, brow0 = tn * 64;
  const int srow = l >> 3;
  const int scol = (((l & 7) * 16) ^ ((l >> 3) << 4)) >> 1;

#define GSTAGE(buf, k0)                                                             \
  {                                                                                 \
    _Pragma("unroll")                                                               \
    for (int c = 0; c < 4; ++c)                                                     \
      gload16(A + (long)(arow0 + w * 32 + c * 8 + srow) * HID + (k0) + scol,        \
              (char*)Al + (buf) * 16384 + w * 4096 + c * 1024);                     \
    _Pragma("unroll")                                                               \
    for (int c = 0; c < 2; ++c)                                                     \
      gload16(W + (long)(brow0 + w * 16 + c * 8 + srow) * HID + (k0) + scol,        \
              (char*)Bl + (buf) * 8192 + w * 2048 + c * 1024);                      \
  }

  GSTAGE(0, 0)
  asm volatile("s_waitcnt vmcnt(0)" ::: "memory");
  __builtin_amdgcn_s_barrier();
  int cur = 0;
  for (int k0 = 0; k0 < HID; k0 += 64) {
    if (k0 + 64 < HID) GSTAGE(cur ^ 1, k0 + 64)
#pragma unroll
    for (int kk = 0; kk < 2; ++kk) {
      bf16x8 af[4], bfr[2];
#pragma unroll
      for (int fm = 0; fm < 4; ++fm) {
        int row = wm * 64 + fm * 16 + (l & 15);
        af[fm] = *reinterpret_cast<const bf16x8*>(
            (char*)Al + cur * 16384 + row * 128 + ((kk * 64 + g * 16) ^ swz));
      }
#pragma unroll
      for (int fn = 0; fn < 2; ++fn) {
        int row = wn * 32 + fn * 16 + (l & 15);
        bfr[fn] = *reinterpret_cast<const bf16x8*>(
            (char*)Bl + cur * 8192 + row * 128 + ((kk * 64 + g * 16) ^ swz));
      }
      __builtin_amdgcn_s_setprio(1);
#pragma unroll
      for (int fm = 0; fm < 4; ++fm)
#pragma unroll
        for (int fn = 0; fn < 2; ++fn)
          acc[fm][fn] = __builtin_amdgcn_mfma_f32_16x16x32_bf16(af[fm], bfr[fn], acc[fm][fn], 0, 0, 0);
      __builtin_amdgcn_s_setprio(0);
    }
    asm volatile("s_waitcnt vmcnt(0)" ::: "memory");
    __builtin_amdgcn_s_barrier();
    cur ^= 1;
  }
#undef GSTAGE

  const int colb = brow0 + wn * 32;
  float bsv[2];
#pragma unroll
  for (int fn = 0; fn < 2; ++fn) bsv[fn] = bias[colb + fn * 16 + (l & 15)];
#pragma unroll
  for (int fm = 0; fm < 4; ++fm)
#pragma unroll
    for (int r = 0; r < 4; ++r) {
      int grow = arow0 + wm * 64 + fm * 16 + (l >> 4) * 4 + r;
#pragma unroll
      for (int fn = 0; fn < 2; ++fn)
        Out[(long)grow * HID + colb + fn * 16 + (l & 15)] = acc[fm][fn][r] + bsv[fn];
    }
}

extern "C" void kernel_launch(void* const* d_in, const int* in_sizes, int n_in,
                              void* d_out, int out_size, void* d_ws, size_t ws_size,
                              hipStream_t stream) {
  const float* x  = (const float*)d_in[0];
  const float* qw = (const float*)d_in[1];
  const float* qb = (const float*)d_in[2];
  const float* kw = (const float*)d_in[3];
  const float* kb = (const float*)d_in[4];
  const float* vw = (const float*)d_in[5];
  const float* vb = (const float*)d_in[6];
  const float* ow = (const float*)d_in[7];
  const float* ob = (const float*)d_in[8];
  float* out = (float*)d_out;

  char* p = (char*)d_ws;
  unsigned short* xb  = (unsigned short*)p; p += (size_t)NTOK * HID * 2;
  unsigned short* wqb = (unsigned short*)p; p += (size_t)HID * HID * 2;
  unsigned short* wkb = (unsigned short*)p; p += (size_t)HID * HID * 2;
  unsigned short* wvb = (unsigned short*)p; p += (size_t)HID * HID * 2;
  unsigned short* wob = (unsigned short*)p; p += (size_t)HID * HID * 2;
  unsigned short* Qb  = (unsigned short*)p; p += (size_t)NTOK * HID * 2;
  unsigned short* Kb  = (unsigned short*)p; p += (size_t)NTOK * HID * 2;
  unsigned short* VTb = (unsigned short*)p; p += (size_t)NTOK * HID * 2;
  float* ct = (float*)p; p += (size_t)SEQ * 32 * 4;
  float* st = (float*)p; p += (size_t)SEQ * 32 * 4;
  unsigned short* Ab  = xb;   // xb dead after gemm_qkv; reuse for attn output

  const int XN = NTOK * HID / 8, WN = HID * HID / 8;
  const int prep_threads = XN + 4 * WN + SEQ * 32;
  prep<<<dim3((prep_threads + 255) / 256), 256, 0, stream>>>(
      x, qw, kw, vw, ow, xb, wqb, wkb, wvb, wob, ct, st);

  gemm_qkv<<<dim3(NTOK / 128, HID / 128, 3), 256, 0, stream>>>(
      xb, wqb, wkb, wvb, qb, kb, vb, ct, st, Qb, Kb, VTb);

  attn<<<dim3(BATCH * NHEADS, SEQ / 128), 256, 0, stream>>>(Qb, Kb, VTb, Ab);

  gemm_o<<<dim3(NTOK / 128, HID / 64), 256, 0, stream>>>(Ab, wob, ob, out);
}

// Round 17
// 102.030 us; speedup vs baseline: 1.1420x; 1.0228x over previous
//
#include <hip/hip_runtime.h>
#include <hip/hip_bf16.h>

// MultiHeadAttention: x[2,2048,1024] fp32 -> QKV proj + RoPE + softmax attn + O proj
// R17: gemm_qkv LDS diet to 48KB (A dbuf + B single-buffered, 2 barriers/iter)
// -> 3 blocks/CU, grid 768 = exact full residency (no tail). attn = R13 (49us),
// gemm_o/prep = R16.

#define SEQ    2048
#define BATCH  2
#define NHEADS 16
#define HDIM   64
#define HID    1024
#define NTOK   (BATCH*SEQ)   // 4096

typedef __bf16 bf16x8 __attribute__((ext_vector_type(8)));
typedef float  f32x4  __attribute__((ext_vector_type(4)));
typedef float  f32x16 __attribute__((ext_vector_type(16)));
typedef unsigned short u16x8 __attribute__((ext_vector_type(8)));
typedef unsigned int   u32x4 __attribute__((ext_vector_type(4)));

__device__ __forceinline__ unsigned short bfc(float x) {
  return __builtin_bit_cast(unsigned short, (__bf16)x);   // native v_cvt (RNE)
}
__device__ __forceinline__ unsigned int pk(float lo, float hi) {
  return (unsigned int)bfc(lo) | ((unsigned int)bfc(hi) << 16);
}
// swap upper 32 lanes of a with lower 32 lanes of b (gfx950)
__device__ __forceinline__ void plswap(unsigned int& a, unsigned int& b) {
  asm volatile("v_permlane32_swap_b32 %0, %1" : "+v"(a), "+v"(b));
}
#define EXP2(x) __builtin_amdgcn_exp2f(x)
#define MFMA32(a, b, c) __builtin_amdgcn_mfma_f32_32x32x16_bf16(a, b, c, 0, 0, 0)

// async global->LDS, 16B per lane. dest = wave-uniform base (+ lane*16 by HW).
__device__ __forceinline__ void gload16(const void* gptr, void* ldsptr) {
  typedef __attribute__((address_space(3))) unsigned int as3_uint;
  typedef const __attribute__((address_space(1))) unsigned int as1_uint;
  __builtin_amdgcn_global_load_lds(
      (as1_uint*)(unsigned long long)gptr,
      (as3_uint*)(unsigned int)(unsigned long long)ldsptr,
      16, 0, 0);
}

__device__ __forceinline__ void cvt8(const float* __restrict__ s,
                                     unsigned short* __restrict__ d, int i) {
  float4 a = *reinterpret_cast<const float4*>(s + i);
  float4 b = *reinterpret_cast<const float4*>(s + i + 4);
  u16x8 o;
  o[0] = bfc(a.x); o[1] = bfc(a.y); o[2] = bfc(a.z); o[3] = bfc(a.w);
  o[4] = bfc(b.x); o[5] = bfc(b.y); o[6] = bfc(b.z); o[7] = bfc(b.w);
  *reinterpret_cast<u16x8*>(d + i) = o;
}

// ---------------- prep: all converts + rope tables in ONE launch ----------------
__global__ __launch_bounds__(256) void prep(
    const float* __restrict__ x,
    const float* __restrict__ qw, const float* __restrict__ kw,
    const float* __restrict__ vw, const float* __restrict__ ow,
    unsigned short* __restrict__ xb,
    unsigned short* __restrict__ wqb, unsigned short* __restrict__ wkb,
    unsigned short* __restrict__ wvb, unsigned short* __restrict__ wob,
    float* __restrict__ ct, float* __restrict__ st)
{
  const int XN = NTOK * HID / 8;   // 524288
  const int WN = HID * HID / 8;    // 131072 (pow2)
  int tid = blockIdx.x * 256 + threadIdx.x;
  if (tid < XN) {
    cvt8(x, xb, tid * 8);
  } else if (tid < XN + 4 * WN) {
    int r = tid - XN;
    int which = r >> 17;                 // / 131072
    int i = (r & (WN - 1)) * 8;
    const float* s = (which == 0) ? qw : (which == 1) ? kw : (which == 2) ? vw : ow;
    unsigned short* d = (which == 0) ? wqb : (which == 1) ? wkb : (which == 2) ? wvb : wob;
    cvt8(s, d, i);
  } else {
    int idx = tid - (XN + 4 * WN);
    if (idx < SEQ * 32) {
      int p = idx >> 5, j = idx & 31;
      float inv = powf(10000.0f, -(float)(2 * j) * (1.0f / 64.0f));
      float a = (float)p * inv;
      ct[idx] = cosf(a);
      st[idx] = sinf(a);
    }
  }
}

// ---------------- QKV GEMM: BK=64, A dbuf + B single (48KB -> 3 blocks/CU) ----------------
__global__ __launch_bounds__(256, 3) void gemm_qkv(
    const unsigned short* __restrict__ X,
    const unsigned short* __restrict__ Wq, const unsigned short* __restrict__ Wk,
    const unsigned short* __restrict__ Wv,
    const float* __restrict__ bq, const float* __restrict__ bk, const float* __restrict__ bv,
    const float* __restrict__ ct, const float* __restrict__ st,
    unsigned short* __restrict__ Qo, unsigned short* __restrict__ Ko,
    unsigned short* __restrict__ VTo)   // V^T: [bh][d][s]
{
  __shared__ unsigned short LSH[24576];  // A[2] @0 (2x8192 shorts = 32KB) | B @16384 (16KB)
  const int z = blockIdx.z;
  const unsigned short* W = (z == 0) ? Wq : (z == 1) ? Wk : Wv;
  const float* bias = (z == 0) ? bq : (z == 1) ? bk : bv;
  const int tm = blockIdx.x, tn = blockIdx.y;
  const int t = threadIdx.x, w = t >> 6, l = t & 63;
  const int wm = w >> 1, wn = w & 1, g = l >> 4;
  const int swz = (l & 7) << 4;

  f32x4 acc[4][4] = {};

  const int arow0 = tm * 128, brow0 = tn * 128;
  // staging coords: wave w covers rows w*32..w*32+31, 4 calls of 8 rows
  const int srow = l >> 3;
  const int scol = (((l & 7) * 16) ^ ((l >> 3) << 4)) >> 1;   // pre-swizzled elem col

#define ASTAGE(buf, k0)                                                             \
  {                                                                                 \
    _Pragma("unroll")                                                               \
    for (int c = 0; c < 4; ++c)                                                     \
      gload16(X + (long)(arow0 + w * 32 + c * 8 + srow) * HID + (k0) + scol,        \
              (char*)LSH + (buf) * 16384 + w * 4096 + c * 1024);                    \
  }
#define BSTAGE(k0)                                                                  \
  {                                                                                 \
    _Pragma("unroll")                                                               \
    for (int c = 0; c < 4; ++c)                                                     \
      gload16(W + (long)(brow0 + w * 32 + c * 8 + srow) * HID + (k0) + scol,        \
              (char*)LSH + 32768 + w * 4096 + c * 1024);                            \
  }

  ASTAGE(0, 0)
  BSTAGE(0)
  asm volatile("s_waitcnt vmcnt(0)" ::: "memory");
  __builtin_amdgcn_s_barrier();
  int cur = 0;
  for (int k0 = 0; k0 < HID; k0 += 64) {
    // read all fragments for this iter from LDS into registers
    bf16x8 af[2][4], bfr[2][4];
#pragma unroll
    for (int kk = 0; kk < 2; ++kk) {
#pragma unroll
      for (int fm = 0; fm < 4; ++fm) {
        int row = wm * 64 + fm * 16 + (l & 15);
        af[kk][fm] = *reinterpret_cast<const bf16x8*>(
            (char*)LSH + cur * 16384 + row * 128 + ((kk * 64 + g * 16) ^ swz));
      }
#pragma unroll
      for (int fn = 0; fn < 4; ++fn) {
        int row = wn * 64 + fn * 16 + (l & 15);
        bfr[kk][fn] = *reinterpret_cast<const bf16x8*>(
            (char*)LSH + 32768 + row * 128 + ((kk * 64 + g * 16) ^ swz));
      }
    }
    // all waves have their B fragments in regs -> safe to overwrite B
    asm volatile("s_waitcnt lgkmcnt(0)" ::: "memory");
    __builtin_amdgcn_s_barrier();
    if (k0 + 64 < HID) {
      ASTAGE(cur ^ 1, k0 + 64)
      BSTAGE(k0 + 64)
    }
    __builtin_amdgcn_s_setprio(1);
#pragma unroll
    for (int kk = 0; kk < 2; ++kk)
#pragma unroll
      for (int fm = 0; fm < 4; ++fm)
#pragma unroll
        for (int fn = 0; fn < 4; ++fn)
          acc[fm][fn] = __builtin_amdgcn_mfma_f32_16x16x32_bf16(af[kk][fm], bfr[kk][fn], acc[fm][fn], 0, 0, 0);
    __builtin_amdgcn_s_setprio(0);
    asm volatile("s_waitcnt vmcnt(0)" ::: "memory");
    __builtin_amdgcn_s_barrier();
    cur ^= 1;
  }
#undef ASTAGE
#undef BSTAGE

  const int colb = brow0 + wn * 64;
  float bsv[4];
#pragma unroll
  for (int fn = 0; fn < 4; ++fn) bsv[fn] = bias[colb + fn * 16 + (l & 15)];

  if (z == 2) {
    // ---- V^T epilogue: C-tile -> LDS transposed (XOR-swizzled) -> coalesced VT store
    __syncthreads();
#pragma unroll
    for (int fm = 0; fm < 4; ++fm) {
      int tok = wm * 64 + fm * 16 + g * 4;
#pragma unroll
      for (int fn = 0; fn < 4; ++fn) {
        int col = wn * 64 + fn * 16 + (l & 15);
        unsigned int u0 = (unsigned int)bfc(acc[fm][fn][0] + bsv[fn]) |
                          ((unsigned int)bfc(acc[fm][fn][1] + bsv[fn]) << 16);
        unsigned int u1 = (unsigned int)bfc(acc[fm][fn][2] + bsv[fn]) |
                          ((unsigned int)bfc(acc[fm][fn][3] + bsv[fn]) << 16);
        uint2 uv; uv.x = u0; uv.y = u1;
        *reinterpret_cast<uint2*>(&LSH[col * 128 + (tok ^ ((col & 7) << 3))]) = uv;
      }
    }
    __syncthreads();
    const int bb = arow0 >> 11, stok = arow0 & (SEQ - 1);
#pragma unroll
    for (int p8 = 0; p8 < 8; ++p8) {
      int col = p8 * 16 + (t >> 4);          // 0..127
      int soff = (t & 15) * 8;
      uint4 v = *reinterpret_cast<const uint4*>(&LSH[col * 128 + (soff ^ ((col & 7) << 3))]);
      int hh = (brow0 + col) >> 6;
      int dd = col & 63;
      unsigned short* dst = VTo + ((long)(bb * NHEADS + hh) * HDIM + dd) * SEQ + stok + soff;
      *reinterpret_cast<uint4*>(dst) = v;
    }
    return;
  }

  // ---- Q/K epilogue: bias + RoPE (+0.125*log2e folded into Q), store [B][H][S][D]
  unsigned short* Out = (z == 0) ? Qo : Ko;
  const int h = colb >> 6;
#pragma unroll
  for (int fm = 0; fm < 4; ++fm) {
#pragma unroll
    for (int r = 0; r < 4; ++r) {
      int grow = arow0 + wm * 64 + fm * 16 + g * 4 + r;
      int b = grow >> 11, sidx = grow & (SEQ - 1);
      unsigned short* ob = Out + ((long)(b * NHEADS + h) * SEQ + sidx) * HDIM;
#pragma unroll
      for (int fn2 = 0; fn2 < 2; ++fn2) {
        int d1 = fn2 * 16 + (l & 15);               // 0..31
        float v1 = acc[fm][fn2][r] + bsv[fn2];
        float v2 = acc[fm][fn2 + 2][r] + bsv[fn2 + 2];
        float c = ct[sidx * 32 + d1], sn = st[sidx * 32 + d1];
        float o1 = v1 * c - v2 * sn;                // d
        float o2 = v2 * c + v1 * sn;                // d+32
        if (z == 0) { o1 *= 0.18033688f; o2 *= 0.18033688f; } // 0.125 * log2(e)
        ob[d1] = bfc(o1);
        ob[d1 + 32] = bfc(o2);
      }
    }
  }
}

// ---------------- flash attention (R13, best measured): KVBLK=128, 16 tiles ----------------
__global__ __launch_bounds__(256, 2) void attn(
    const unsigned short* __restrict__ Qb,
    const unsigned short* __restrict__ Kb,
    const unsigned short* __restrict__ VTb,
    unsigned short* __restrict__ Ob)   // [NTOK][HID] bf16
{
  __shared__ unsigned short Kl[2][128 * 64];   // [key][d], swizzle ^((key&7)<<4)
  __shared__ unsigned short Vl[3][8192];       // [half][d][key64], swizzle ^((d&7)<<4)
  const int bh = blockIdx.x, qt = blockIdx.y;
  const int b = bh >> 4, h = bh & 15;
  const int t = threadIdx.x, w = t >> 6, l = t & 63;
  const long hb = (long)bh * SEQ * HDIM;
  const int hh = l >> 5;          // half-wave index
  const int swz = (l & 7) << 4;   // byte swizzle for row-reads (row&7 == l&7)

  // Q as B-operand: col=l&31 (q), k(d) = dc*16 + hh*8 + j
  const int q0 = qt * 128 + w * 32;
  bf16x8 qf[4];
#pragma unroll
  for (int dc = 0; dc < 4; ++dc)
    qf[dc] = *reinterpret_cast<const bf16x8*>(
        Qb + hb + (long)(q0 + (l & 31)) * HDIM + dc * 16 + hh * 8);

  f32x16 oacc[2] = {};           // O^T d-blocks; col=q=l&31
  f32x16 oaccE = {};             // every reg = row-sum of P for q=l&31
  const f32x16 FZ16 = {};

  // ones A-fragment (bf16 1.0 x8)
  u32x4 ou; ou[0] = 0x3F803F80u; ou[1] = 0x3F803F80u; ou[2] = 0x3F803F80u; ou[3] = 0x3F803F80u;
  const bf16x8 ones8 = __builtin_bit_cast(bf16x8, ou);

  // staging pointers (advance by one 128-key tile per STAGE)
  const int srow = l >> 3;
  const int scol = (((l & 7) * 16) ^ ((l >> 3) << 4)) >> 1;
  const unsigned short* kp0 = Kb + hb + (long)(w * 32 + srow) * HDIM + scol;
  const unsigned short* kp1 = kp0 + 8 * HDIM;
  const unsigned short* kp2 = kp0 + 16 * HDIM;
  const unsigned short* kp3 = kp0 + 24 * HDIM;
  const unsigned short* vp0 = VTb + hb + (long)(w * 16 + srow) * SEQ + scol;   // half0 rows w16..+7
  const unsigned short* vp1 = vp0 + 8 * SEQ;                                   // half0 rows +8
  const unsigned short* vp2 = vp0 + 64;                                        // half1
  const unsigned short* vp3 = vp1 + 64;

#define STAGE(kbuf, vbuf)                                                   \
  {                                                                         \
    gload16(kp0, (char*)Kl + (kbuf) * 16384 + w * 4096);                    \
    gload16(kp1, (char*)Kl + (kbuf) * 16384 + w * 4096 + 1024);             \
    gload16(kp2, (char*)Kl + (kbuf) * 16384 + w * 4096 + 2048);             \
    gload16(kp3, (char*)Kl + (kbuf) * 16384 + w * 4096 + 3072);             \
    gload16(vp0, (char*)Vl + (vbuf) * 16384 + w * 2048);                    \
    gload16(vp1, (char*)Vl + (vbuf) * 16384 + w * 2048 + 1024);             \
    gload16(vp2, (char*)Vl + (vbuf) * 16384 + 8192 + w * 2048);             \
    gload16(vp3, (char*)Vl + (vbuf) * 16384 + 8192 + w * 2048 + 1024);      \
    kp0 += 128 * HDIM; kp1 += 128 * HDIM; kp2 += 128 * HDIM; kp3 += 128 * HDIM; \
    vp0 += 128; vp1 += 128; vp2 += 128; vp3 += 128;                         \
  }

// S^T = K Q : sa[blk] covers keys 32blk..32blk+31 for this wave's 32 q
#define QK(kbuf)                                                                  \
  _Pragma("unroll")                                                               \
  for (int blk = 0; blk < 4; ++blk) {                                             \
    const char* kb_ = (char*)Kl + (kbuf) * 16384 + (32 * blk + (l & 31)) * 128;   \
    bf16x8 kf0 = *reinterpret_cast<const bf16x8*>(kb_ + ((0 * 32 + hh * 16) ^ swz)); \
    sa[blk] = MFMA32(kf0, qf[0], FZ16);                                           \
    bf16x8 kf1 = *reinterpret_cast<const bf16x8*>(kb_ + ((1 * 32 + hh * 16) ^ swz)); \
    sa[blk] = MFMA32(kf1, qf[1], sa[blk]);                                        \
    bf16x8 kf2 = *reinterpret_cast<const bf16x8*>(kb_ + ((2 * 32 + hh * 16) ^ swz)); \
    sa[blk] = MFMA32(kf2, qf[2], sa[blk]);                                        \
    bf16x8 kf3 = *reinterpret_cast<const bf16x8*>(kb_ + ((3 * 32 + hh * 16) ^ swz)); \
    sa[blk] = MFMA32(kf3, qf[3], sa[blk]);                                        \
  }

#define SOFTEXP                                                                   \
  _Pragma("unroll")                                                               \
  for (int blk = 0; blk < 4; ++blk)                                               \
    _Pragma("unroll")                                                             \
    for (int r = 0; r < 16; ++r) sa[blk][r] = EXP2(sa[blk][r]);

// build PV B-frags in-register: pB[2blk+c] = keys 16(2blk+c)+8h+{0..7} for q=l&31
#define PBUILD                                                                    \
  _Pragma("unroll")                                                               \
  for (int blk = 0; blk < 4; ++blk) {                                             \
    unsigned int w0a = pk(sa[blk][0], sa[blk][1]);                                \
    unsigned int w1a = pk(sa[blk][2], sa[blk][3]);                                \
    unsigned int w0b = pk(sa[blk][4], sa[blk][5]);                                \
    unsigned int w1b = pk(sa[blk][6], sa[blk][7]);                                \
    unsigned int w0c = pk(sa[blk][8], sa[blk][9]);                                \
    unsigned int w1c = pk(sa[blk][10], sa[blk][11]);                              \
    unsigned int w0d = pk(sa[blk][12], sa[blk][13]);                              \
    unsigned int w1d = pk(sa[blk][14], sa[blk][15]);                              \
    plswap(w0a, w0b); plswap(w1a, w1b);                                           \
    plswap(w0c, w0d); plswap(w1c, w1d);                                           \
    u32x4 f0; f0[0] = w0a; f0[1] = w1a; f0[2] = w0b; f0[3] = w1b;                 \
    u32x4 f1; f1[0] = w0c; f1[1] = w1c; f1[2] = w0d; f1[3] = w1d;                 \
    pB[2 * blk + 0] = __builtin_bit_cast(bf16x8, f0);                             \
    pB[2 * blk + 1] = __builtin_bit_cast(bf16x8, f1);                             \
  }

// O^T += V^T P ; oaccE += 1*P (row-sum). kc 0..7 over 128 keys; half = kc>>2.
#define PVSTEP(vbuf)                                                              \
  _Pragma("unroll")                                                               \
  for (int db = 0; db < 2; ++db) {                                                \
    _Pragma("unroll")                                                             \
    for (int kc = 0; kc < 8; ++kc) {                                              \
      const char* vb_ = (char*)Vl + (vbuf) * 16384 + (kc >> 2) * 8192 +           \
                        (32 * db + (l & 31)) * 128 + (((kc & 3) * 32 + hh * 16) ^ swz); \
      bf16x8 vf = *reinterpret_cast<const bf16x8*>(vb_);                          \
      oacc[db] = MFMA32(vf, pB[kc], oacc[db]);                                    \
    }                                                                             \
  }                                                                               \
  _Pragma("unroll")                                                               \
  for (int kc = 0; kc < 8; ++kc) oaccE = MFMA32(ones8, pB[kc], oaccE);

#define ITER(KB, VR, VW)                                   \
  {                                                        \
    STAGE(KB ^ 1, VW)                                      \
    __builtin_amdgcn_s_setprio(1);                         \
    QK(KB)                                                 \
    PVSTEP(VR)                                             \
    __builtin_amdgcn_s_setprio(0);                         \
    SOFTEXP                                                \
    PBUILD                                                 \
    asm volatile("s_waitcnt vmcnt(0)" ::: "memory");       \
    __builtin_amdgcn_s_barrier();                          \
  }
#define ITER_NOSTAGE(KB, VR)                               \
  {                                                        \
    __builtin_amdgcn_s_setprio(1);                         \
    QK(KB)                                                 \
    PVSTEP(VR)                                             \
    __builtin_amdgcn_s_setprio(0);                         \
    SOFTEXP                                                \
    PBUILD                                                 \
    asm volatile("s_waitcnt vmcnt(0)" ::: "memory");       \
    __builtin_amdgcn_s_barrier();                          \
  }

  f32x16 sa[4];
  bf16x8 pB[8];

  // prologue: stage tile 0 into K[0],V[0]
  STAGE(0, 0)
  asm volatile("s_waitcnt vmcnt(0)" ::: "memory");
  __builtin_amdgcn_s_barrier();

  // peeled t=0: stage tile 1 -> K[1],V[1]; QK(0); exp2+PBUILD; no PV yet
  STAGE(1, 1)
  __builtin_amdgcn_s_setprio(1);
  QK(0)
  __builtin_amdgcn_s_setprio(0);
  SOFTEXP
  PBUILD
  asm volatile("s_waitcnt vmcnt(0)" ::: "memory");
  __builtin_amdgcn_s_barrier();

  // main: t=1..14 with (KB=t&1, VR=(t-1)%3, VW=(t+1)%3); period 6
  for (int m = 0; m < 2; ++m) {
    ITER(1, 0, 2)
    ITER(0, 1, 0)
    ITER(1, 2, 1)
    ITER(0, 0, 2)
    ITER(1, 1, 0)
    ITER(0, 2, 1)
  }
  ITER(1, 0, 2)        // t=13
  ITER(0, 1, 0)        // t=14 (stages tile 15 -> V[0])
  ITER_NOSTAGE(1, 2)   // t=15 (QK(15), PV(14))

  // epilogue: PV of tile 15 (P in pB, V in Vl[0])
  __builtin_amdgcn_s_setprio(1);
  PVSTEP(0)
  __builtin_amdgcn_s_setprio(0);

#undef STAGE
#undef QK
#undef SOFTEXP
#undef PBUILD
#undef PVSTEP
#undef ITER
#undef ITER_NOSTAGE

  // ---- normalize + store O^T (lane owns q = q0+(l&31); d = (r&3)+8(r>>2)+4hh+32db)
  {
    float inv = 1.0f / oaccE[0];
    int q = q0 + (l & 31);
    unsigned short* op = Ob + (long)(b * SEQ + q) * HID + h * HDIM;
#pragma unroll
    for (int db = 0; db < 2; ++db)
#pragma unroll
      for (int a = 0; a < 4; ++a) {
        int d = 8 * a + 4 * hh + 32 * db;
        unsigned int lo = pk(oacc[db][4 * a + 0] * inv, oacc[db][4 * a + 1] * inv);
        unsigned int hi2 = pk(oacc[db][4 * a + 2] * inv, oacc[db][4 * a + 3] * inv);
        uint2 uv; uv.x = lo; uv.y = hi2;
        *reinterpret_cast<uint2*>(op + d) = uv;
      }
  }
}

// ---------------- output projection: BK=64 dbuf, 128x64 tile ----------------
__global__ __launch_bounds__(256, 3) void gemm_o(
    const unsigned short* __restrict__ A,
    const unsigned short* __restrict__ W,
    const float* __restrict__ bias,
    float* __restrict__ Out)
{
  __shared__ unsigned short Al[2][128 * 64];   // 2x16KB, 128B rows swizzled
  __shared__ unsigned short Bl[2][64 * 64];    // 2x8KB
  const int tm = blockIdx.x, tn = blockIdx.y;
  const int t = threadIdx.x, w = t >> 6, l = t & 63;
  const int wm = w >> 1, wn = w & 1, g = l >> 4;
  const int swz = (l & 7) << 4;

  f32x4 acc[4][2] = {};
  const int arow0 = tm * 128, brow0 = tn * 64;
  const int srow = l >> 3;
  const int scol = (((l & 7) * 16) ^ ((l >> 3) << 4)) >> 1;

#define GSTAGE(buf, k0)                                                             \
  {                                                                                 \
    _Pragma("unroll")                                                               \
    for (int c = 0; c < 4; ++c)                                                     \
      gload16(A + (long)(arow0 + w * 32 + c * 8 + srow) * HID + (k0) + scol,        \
              (char*)Al + (buf) * 16384 + w * 4096 + c * 1024);                     \
    _Pragma("unroll")                                                               \
    for (int c = 0; c < 2; ++c)                                                     \
      gload16(W + (long)(brow0 + w * 16 + c * 8 + srow) * HID + (k0) + scol,        \
              (char*)Bl + (buf) * 8192 + w * 2048 + c * 1024);                      \
  }

  GSTAGE(0, 0)
  asm volatile("s_waitcnt vmcnt(0)" ::: "memory");
  __builtin_amdgcn_s_barrier();
  int cur = 0;
  for (int k0 = 0; k0 < HID; k0 += 64) {
    if (k0 + 64 < HID) GSTAGE(cur ^ 1, k0 + 64)
#pragma unroll
    for (int kk = 0; kk < 2; ++kk) {
      bf16x8 af[4], bfr[2];
#pragma unroll
      for (int fm = 0; fm < 4; ++fm) {
        int row = wm * 64 + fm * 16 + (l & 15);
        af[fm] = *reinterpret_cast<const bf16x8*>(
            (char*)Al + cur * 16384 + row * 128 + ((kk * 64 + g * 16) ^ swz));
      }
#pragma unroll
      for (int fn = 0; fn < 2; ++fn) {
        int row = wn * 32 + fn * 16 + (l & 15);
        bfr[fn] = *reinterpret_cast<const bf16x8*>(
            (char*)Bl + cur * 8192 + row * 128 + ((kk * 64 + g * 16) ^ swz));
      }
      __builtin_amdgcn_s_setprio(1);
#pragma unroll
      for (int fm = 0; fm < 4; ++fm)
#pragma unroll
        for (int fn = 0; fn < 2; ++fn)
          acc[fm][fn] = __builtin_amdgcn_mfma_f32_16x16x32_bf16(af[fm], bfr[fn], acc[fm][fn], 0, 0, 0);
      __builtin_amdgcn_s_setprio(0);
    }
    asm volatile("s_waitcnt vmcnt(0)" ::: "memory");
    __builtin_amdgcn_s_barrier();
    cur ^= 1;
  }
#undef GSTAGE

  const int colb = brow0 + wn * 32;
  float bsv[2];
#pragma unroll
  for (int fn = 0; fn < 2; ++fn) bsv[fn] = bias[colb + fn * 16 + (l & 15)];
#pragma unroll
  for (int fm = 0; fm < 4; ++fm)
#pragma unroll
    for (int r = 0; r < 4; ++r) {
      int grow = arow0 + wm * 64 + fm * 16 + (l >> 4) * 4 + r;
#pragma unroll
      for (int fn = 0; fn < 2; ++fn)
        Out[(long)grow * HID + colb + fn * 16 + (l & 15)] = acc[fm][fn][r] + bsv[fn];
    }
}

extern "C" void kernel_launch(void* const* d_in, const int* in_sizes, int n_in,
                              void* d_out, int out_size, void* d_ws, size_t ws_size,
                              hipStream_t stream) {
  const float* x  = (const float*)d_in[0];
  const float* qw = (const float*)d_in[1];
  const float* qb = (const float*)d_in[2];
  const float* kw = (const float*)d_in[3];
  const float* kb = (const float*)d_in[4];
  const float* vw = (const float*)d_in[5];
  const float* vb = (const float*)d_in[6];
  const float* ow = (const float*)d_in[7];
  const float* ob = (const float*)d_in[8];
  float* out = (float*)d_out;

  char* p = (char*)d_ws;
  unsigned short* xb  = (unsigned short*)p; p += (size_t)NTOK * HID * 2;
  unsigned short* wqb = (unsigned short*)p; p += (size_t)HID * HID * 2;
  unsigned short* wkb = (unsigned short*)p; p += (size_t)HID * HID * 2;
  unsigned short* wvb = (unsigned short*)p; p += (size_t)HID * HID * 2;
  unsigned short* wob = (unsigned short*)p; p += (size_t)HID * HID * 2;
  unsigned short* Qb  = (unsigned short*)p; p += (size_t)NTOK * HID * 2;
  unsigned short* Kb  = (unsigned short*)p; p += (size_t)NTOK * HID * 2;
  unsigned short* VTb = (unsigned short*)p; p += (size_t)NTOK * HID * 2;
  float* ct = (float*)p; p += (size_t)SEQ * 32 * 4;
  float* st = (float*)p; p += (size_t)SEQ * 32 * 4;
  unsigned short* Ab  = xb;   // xb dead after gemm_qkv; reuse for attn output

  const int XN = NTOK * HID / 8, WN = HID * HID / 8;
  const int prep_threads = XN + 4 * WN + SEQ * 32;
  prep<<<dim3((prep_threads + 255) / 256), 256, 0, stream>>>(
      x, qw, kw, vw, ow, xb, wqb, wkb, wvb, wob, ct, st);

  gemm_qkv<<<dim3(NTOK / 128, HID / 128, 3), 256, 0, stream>>>(
      xb, wqb, wkb, wvb, qb, kb, vb, ct, st, Qb, Kb, VTb);

  attn<<<dim3(BATCH * NHEADS, SEQ / 128), 256, 0, stream>>>(Qb, Kb, VTb, Ab);

  gemm_o<<<dim3(NTOK / 128, HID / 64), 256, 0, stream>>>(Ab, wob, ob, out);
}